// Round 4
// baseline (624.238 us; speedup 1.0000x reference)
//
#include <hip/hip_runtime.h>
#include <stdint.h>

typedef unsigned short ushort_t;
typedef __attribute__((ext_vector_type(8))) short bf16x8;
typedef __attribute__((ext_vector_type(4))) float f32x4;

#define EPS 1e-6f

__device__ __forceinline__ float b2f(ushort_t u) {
    union { uint32_t i; float f; } v; v.i = ((uint32_t)u) << 16; return v.f;
}
__device__ __forceinline__ ushort_t f2b(float f) {
    union { float f; uint32_t i; } v; v.f = f;
    uint32_t x = v.i;
    uint32_t r = (x + 0x7fffu + ((x >> 16) & 1u)) >> 16;
    return (ushort_t)r;
}

__device__ __forceinline__ void async_copy16(const void* g, void* l) {
    __builtin_amdgcn_global_load_lds(
        (const __attribute__((address_space(1))) uint32_t*)(uintptr_t)g,
        (__attribute__((address_space(3))) uint32_t*)(uintptr_t)l,
        16, 0, 0);
}

// ---------------- fused f32 -> bf16 casts (4 tensors, one dispatch) ----------------
__global__ __launch_bounds__(256) void cast4_k(
    const float* __restrict__ s0, ushort_t* __restrict__ d0, int n0,
    const float* __restrict__ s1, ushort_t* __restrict__ d1, int n1,
    const float* __restrict__ s2, ushort_t* __restrict__ d2, int n2,
    const float* __restrict__ s3, ushort_t* __restrict__ d3) {
    int j = blockIdx.x * 256 + threadIdx.x;
    const float* s; ushort_t* d;
    if (j < n0) { s = s0; d = d0; }
    else if ((j -= n0) < n1) { s = s1; d = d1; }
    else if ((j -= n1) < n2) { s = s2; d = d2; }
    else { j -= n2; s = s3; d = d3; }
    float4 v = ((const float4*)s)[j];
    ushort4 o;
    o.x = f2b(v.x); o.y = f2b(v.y); o.z = f2b(v.z); o.w = f2b(v.w);
    ((ushort4*)d)[j] = o;
}

// ---- batched transpose + cast: src (batch,R,C) f32 -> dst (batch,C,R) bf16 ----
__global__ __launch_bounds__(256) void transpose_cast_k(const float* __restrict__ src,
                                                        ushort_t* __restrict__ dst,
                                                        int R, int C) {
    __shared__ float tile[32][33];
    int bat = blockIdx.z;
    int c0 = blockIdx.x * 32, r0 = blockIdx.y * 32;
    const float* s = src + (size_t)bat * R * C;
    ushort_t* d = dst + (size_t)bat * R * C;
    int tx = threadIdx.x, ty = threadIdx.y;   // blockDim (8,32)
    float4 v = *(const float4*)&s[(size_t)(r0 + ty) * C + c0 + tx * 4];
    tile[ty][tx * 4 + 0] = v.x;
    tile[ty][tx * 4 + 1] = v.y;
    tile[ty][tx * 4 + 2] = v.z;
    tile[ty][tx * 4 + 3] = v.w;
    __syncthreads();
    ushort4 o;
    o.x = f2b(tile[tx * 4 + 0][ty]);
    o.y = f2b(tile[tx * 4 + 1][ty]);
    o.z = f2b(tile[tx * 4 + 2][ty]);
    o.w = f2b(tile[tx * 4 + 3][ty]);
    *(ushort4*)&d[(size_t)(c0 + ty) * R + r0 + tx * 4] = o;
}

// ---------------- MFMA GEMM: C[m,n] = sum_k A[m,k] * B[n,k], bf16 in, f32 acc --------
// v4: 64x128 tile (BM=64, BN=128, BK=64) -> LDS 48 KB -> 3 blocks/CU (was 2),
//     doubled grid for TLP. Same verified sync structure as v3b: double-buffered,
//     counted vmcnt(6), raw s_barrier pair + sched_barrier(0) pins, 8-slot XOR
//     swizzle (pre-swizzled global source + swizzled ds_read), XCD-aware remap
//     (generalized to gridDim.x = 16), plane-split output via czoff.
// MODE 0: A = Aa (M x lda)
// MODE 1: A(m,k) = k<3072 ? x[m,3072]+k : dbf[m,8192] + g*1024 + (k-3072), g = n0/1024
// MODE 2: A(m,k) = hbf[m,8192] + g*1024 + k, g = n0/3072
template <int MODE, bool OUT_BF16>
__global__ __launch_bounds__(256) void gemm_bt_k(
    const ushort_t* __restrict__ Aa, const ushort_t* __restrict__ Ab,
    const ushort_t* __restrict__ Bw,
    float* __restrict__ Cf, ushort_t* __restrict__ Cb,
    int lda, int ldb, int ldc, int Ksl, int k0base, int czoff) {
    __shared__ __align__(16) ushort_t As[2][64 * 64];
    __shared__ __align__(16) ushort_t Bs[2][128 * 64];
    const int tid = threadIdx.x;

    // XCD-aware remap: nxy % 8 == 0 in all launches; bijective.
    const int gx = gridDim.x;                    // 16 in all launches
    const int nxy = gx * gridDim.y;
    const int flat = blockIdx.x + blockIdx.y * gx;
    const int cpx = nxy >> 3;
    const int L = (flat & 7) * cpx + (flat >> 3);
    const int bm = L % gx, bn = L / gx;
    const int bz = blockIdx.z;
    const int k0 = k0base + bz * Ksl;
    const int m0 = bm * 64, n0 = bn * 128;
    const int cz = bz * czoff;                  // plane-split column shift
    const int lane = tid & 63, w = tid >> 6;
    const int wm = (w & 1) * 32, wn = (w >> 1) * 64;

    f32x4 acc[2][4];
#pragma unroll
    for (int i = 0; i < 2; i++)
#pragma unroll
        for (int j = 0; j < 4; j++) acc[i][j] = (f32x4){0.f, 0.f, 0.f, 0.f};

    auto a_ptr = [&](int m, int kk) -> const ushort_t* {
        if (MODE == 0) {
            return Aa + (size_t)m * lda + kk;
        } else if (MODE == 1) {
            if (kk < 3072) return Aa + (size_t)m * 3072 + kk;
            int g = n0 >> 10;
            return Ab + (size_t)m * 8192 + g * 1024 + (kk - 3072);
        } else {
            int g = n0 / 3072;
            return Aa + (size_t)m * 8192 + g * 1024 + kk;
        }
    };

    // Staging geometry: thread -> (row = tid>>3 in 0..31, slot = tid&7).
    // LDS dest linear in tid (global_load_lds requirement); the 8-slot XOR
    // swizzle is applied on the GLOBAL source k-chunk (both-sides involution).
    const int srow = tid >> 3;
    const int sslot = tid & 7;
    const int gco = (sslot ^ (srow & 7)) << 3;   // swizzled global k-chunk (elems)
    const int lco = sslot << 3;                  // linear LDS chunk (elems)

    auto stage = [&](int buf, int kk) {          // 6 global_load_lds per thread
#pragma unroll
        for (int p = 0; p < 2; ++p) {
            int r = (p << 5) + srow;             // r&7 == srow&7
            async_copy16(a_ptr(m0 + r, kk + gco), &As[buf][r * 64 + lco]);
        }
#pragma unroll
        for (int p = 0; p < 4; ++p) {
            int r = (p << 5) + srow;
            async_copy16(Bw + (size_t)(n0 + r) * ldb + kk + gco, &Bs[buf][r * 64 + lco]);
        }
    };

    const int nt = Ksl >> 6;                     // 64-wide K tiles
    stage(0, k0);
    __builtin_amdgcn_sched_barrier(0);           // pin prologue stage above loop

    const int qc = lane >> 4;                    // k-chunk within 32 (0..3)
    const int rl = lane & 15;
    int cur = 0;

    for (int t = 0; t < nt; ++t) {
        if (t + 1 < nt) {
            stage(cur ^ 1, k0 + ((t + 1) << 6)); // issue next tile (6 loads)
            asm volatile("s_waitcnt vmcnt(6)" ::: "memory");  // wait tile t only
        } else {
            asm volatile("s_waitcnt vmcnt(0)" ::: "memory");
        }
        __builtin_amdgcn_s_barrier();            // publish tile t to all waves
        __builtin_amdgcn_sched_barrier(0);

#pragma unroll
        for (int h = 0; h < 2; ++h) {            // two K=32 halves of the tile
            bf16x8 af[2], bfr[4];
#pragma unroll
            for (int i = 0; i < 2; i++) {
                int ra = wm + i * 16 + rl;
                int slot = ((h << 2) + qc) ^ (ra & 7);
                af[i] = *(const bf16x8*)&As[cur][ra * 64 + (slot << 3)];
            }
#pragma unroll
            for (int j = 0; j < 4; j++) {
                int rb = wn + j * 16 + rl;
                int slot = ((h << 2) + qc) ^ (rb & 7);
                bfr[j] = *(const bf16x8*)&Bs[cur][rb * 64 + (slot << 3)];
            }
#pragma unroll
            for (int i = 0; i < 2; i++)
#pragma unroll
                for (int j = 0; j < 4; j++)
                    acc[i][j] = __builtin_amdgcn_mfma_f32_16x16x32_bf16(af[i], bfr[j], acc[i][j], 0, 0, 0);
        }

        if (t + 1 < nt) {
            __builtin_amdgcn_sched_barrier(0);   // keep all tile-t reads above
            __builtin_amdgcn_s_barrier();        // reads done before overwrite
            __builtin_amdgcn_sched_barrier(0);   // keep next stage below
            cur ^= 1;
        }
    }

    const int cr = (lane >> 4) * 4, cc = lane & 15;
#pragma unroll
    for (int i = 0; i < 2; i++) {
#pragma unroll
        for (int j = 0; j < 4; j++) {
#pragma unroll
            for (int r = 0; r < 4; r++) {
                int row = m0 + wm + i * 16 + cr + r;
                int col = n0 + cz + wn + j * 16 + cc;
                float v = acc[i][j][r];
                if (OUT_BF16) {
                    Cb[(size_t)row * ldc + col] = f2b(v);
                } else {
                    Cf[(size_t)row * ldc + col] = v;
                }
            }
        }
    }
}

// ---------------- branch 3 (K=2): xacc[:, 6144:7168] = a_norm @ W3.T ----------------
__global__ __launch_bounds__(256) void branch3_k(const float* __restrict__ act,
                                                 const float* __restrict__ W3,
                                                 float* __restrict__ xacc) {
    int idx = blockIdx.x * 256 + threadIdx.x;   // over B*1024
    int b = idx >> 10, h = idx & 1023;
    float a0 = act[b * 2 + 0], a1 = act[b * 2 + 1];
    a0 = a0 / fmaxf(1.f, fabsf(a0));
    a1 = a1 / fmaxf(1.f, fabsf(a1));
    float v = a0 * W3[h * 2 + 0] + a1 * W3[h * 2 + 1];
    xacc[(size_t)b * 7168 + 6144 + h] = v;
}

// ------- RMSNorm(1024)+SiLU per (b, chunk) with plane reduction, out bf16 -------
// xacc row layout (7168 f32): [c0: 4 planes x1024][c1: 2 planes x1024][c2: 1x1024]
__global__ __launch_bounds__(256) void norm_silu_1024_k(
    const float* __restrict__ xacc,
    const float* __restrict__ b1, const float* __restrict__ s1,
    const float* __restrict__ b2, const float* __restrict__ s2,
    const float* __restrict__ b3, const float* __restrict__ s3,
    ushort_t* __restrict__ xbf) {
    int b = blockIdx.x, c = blockIdx.y, tid = threadIdx.x;
    const float* bias = (c == 0) ? b1 : (c == 1) ? b2 : b3;
    const float* scl  = (c == 0) ? s1 : (c == 1) ? s2 : s3;
    const float* row = xacc + (size_t)b * 7168 + ((c == 0) ? 0 : (c == 1) ? 4096 : 6144);
    const int np = (c == 0) ? 4 : (c == 1) ? 2 : 1;
    float4 v = ((const float4*)row)[tid];
#pragma unroll 4
    for (int p = 1; p < np; ++p) {
        float4 t = ((const float4*)(row + p * 1024))[tid];
        v.x += t.x; v.y += t.y; v.z += t.z; v.w += t.w;
    }
    float4 bb = ((const float4*)bias)[tid];
    v.x += bb.x; v.y += bb.y; v.z += bb.z; v.w += bb.w;
    float ss = v.x * v.x + v.y * v.y + v.z * v.z + v.w * v.w;
#pragma unroll
    for (int off = 32; off > 0; off >>= 1) ss += __shfl_down(ss, off, 64);
    __shared__ float wsum[4];
    int lane = tid & 63, wid = tid >> 6;
    if (lane == 0) wsum[wid] = ss;
    __syncthreads();
    float tot = wsum[0] + wsum[1] + wsum[2] + wsum[3];
    float rms = rsqrtf(tot * (1.0f / 1024.0f) + EPS);
    float4 sc = ((const float4*)scl)[tid];
    float o0 = v.x * rms * sc.x; o0 = o0 / (1.f + __expf(-o0));
    float o1 = v.y * rms * sc.y; o1 = o1 / (1.f + __expf(-o1));
    float o2 = v.z * rms * sc.z; o2 = o2 / (1.f + __expf(-o2));
    float o3 = v.w * rms * sc.w; o3 = o3 / (1.f + __expf(-o3));
    ushort4 o; o.x = f2b(o0); o.y = f2b(o1); o.z = f2b(o2); o.w = f2b(o3);
    ((ushort4*)(xbf + (size_t)b * 3072 + c * 1024))[tid] = o;
}

// ---------------- RMSNorm(8192)+SiLU per row, out bf16 ----------------
__global__ __launch_bounds__(256) void norm_silu_8192_k(const float* __restrict__ hpre,
                                                        const float* __restrict__ bb1,
                                                        const float* __restrict__ sb1,
                                                        ushort_t* __restrict__ hbf) {
    int b = blockIdx.x, tid = threadIdx.x;
    const float4* src = (const float4*)(hpre + (size_t)b * 8192);
    float4 v[8];
    float ss = 0.f;
#pragma unroll
    for (int k = 0; k < 8; k++) {
        float4 t = src[tid + k * 256];
        float4 bv = ((const float4*)bb1)[tid + k * 256];
        t.x += bv.x; t.y += bv.y; t.z += bv.z; t.w += bv.w;
        v[k] = t;
        ss += t.x * t.x + t.y * t.y + t.z * t.z + t.w * t.w;
    }
#pragma unroll
    for (int off = 32; off > 0; off >>= 1) ss += __shfl_down(ss, off, 64);
    __shared__ float wsum[4];
    int lane = tid & 63, wid = tid >> 6;
    if (lane == 0) wsum[wid] = ss;
    __syncthreads();
    float tot = wsum[0] + wsum[1] + wsum[2] + wsum[3];
    float rms = rsqrtf(tot * (1.0f / 8192.0f) + EPS);
    ushort_t* dst = hbf + (size_t)b * 8192;
#pragma unroll
    for (int k = 0; k < 8; k++) {
        float4 sv = ((const float4*)sb1)[tid + k * 256];
        float o0 = v[k].x * rms * sv.x; o0 = o0 / (1.f + __expf(-o0));
        float o1 = v[k].y * rms * sv.y; o1 = o1 / (1.f + __expf(-o1));
        float o2 = v[k].z * rms * sv.z; o2 = o2 / (1.f + __expf(-o2));
        float o3 = v[k].w * rms * sv.w; o3 = o3 / (1.f + __expf(-o3));
        ushort4 o; o.x = f2b(o0); o.y = f2b(o1); o.z = f2b(o2); o.w = f2b(o3);
        ((ushort4*)dst)[tid + k * 256] = o;
    }
}

// ---------------- gate combine ----------------
__global__ __launch_bounds__(256) void gates_k(const ushort_t* __restrict__ y,
                                               const float* __restrict__ bb2,
                                               const float* __restrict__ deter,
                                               float* __restrict__ out) {
    int idx = blockIdx.x * 256 + threadIdx.x;    // over B*8192/4
    int f = idx * 4;
    int b = f >> 13, d = f & 8191;
    int g = d >> 10, j = d & 1023;
    size_t ybase = (size_t)b * 24576 + g * 3072 + j;
    ushort4 rv = *(const ushort4*)(y + ybase);
    ushort4 cv = *(const ushort4*)(y + ybase + 1024);
    ushort4 uv = *(const ushort4*)(y + ybase + 2048);
    float4 bbr = *(const float4*)(bb2 + g * 3072 + j);
    float4 bbc = *(const float4*)(bb2 + g * 3072 + 1024 + j);
    float4 bbu = *(const float4*)(bb2 + g * 3072 + 2048 + j);
    float4 dv = *(const float4*)(deter + f);
    float rr[4] = {b2f(rv.x) + bbr.x, b2f(rv.y) + bbr.y, b2f(rv.z) + bbr.z, b2f(rv.w) + bbr.w};
    float cc[4] = {b2f(cv.x) + bbc.x, b2f(cv.y) + bbc.y, b2f(cv.z) + bbc.z, b2f(cv.w) + bbc.w};
    float uu[4] = {b2f(uv.x) + bbu.x, b2f(uv.y) + bbu.y, b2f(uv.z) + bbu.z, b2f(uv.w) + bbu.w};
    float dd[4] = {dv.x, dv.y, dv.z, dv.w};
    float oo[4];
#pragma unroll
    for (int t = 0; t < 4; t++) {
        float reset = 1.f / (1.f + __expf(-rr[t]));
        float cand = tanhf(reset * cc[t]);
        float upd = 1.f / (1.f + __expf(-(uu[t] - 1.f)));
        oo[t] = upd * cand + (1.f - upd) * dd[t];
    }
    float4 o; o.x = oo[0]; o.y = oo[1]; o.z = oo[2]; o.w = oo[3];
    *(float4*)(out + f) = o;
}

extern "C" void kernel_launch(void* const* d_in, const int* in_sizes, int n_in,
                              void* d_out, int out_size, void* d_ws, size_t ws_size,
                              hipStream_t stream) {
    const float* deter = (const float*)d_in[0];
    const float* stoch = (const float*)d_in[1];
    const float* action = (const float*)d_in[2];
    const float* W1 = (const float*)d_in[3];
    const float* b1 = (const float*)d_in[4];
    const float* s1 = (const float*)d_in[5];
    const float* W2 = (const float*)d_in[6];
    const float* b2 = (const float*)d_in[7];
    const float* s2 = (const float*)d_in[8];
    const float* W3 = (const float*)d_in[9];
    const float* b3 = (const float*)d_in[10];
    const float* s3 = (const float*)d_in[11];
    const float* Wb1 = (const float*)d_in[12];
    const float* bb1 = (const float*)d_in[13];
    const float* sb1 = (const float*)d_in[14];
    const float* Wb2 = (const float*)d_in[15];
    const float* bb2 = (const float*)d_in[16];
    float* out = (float*)d_out;

    char* ws = (char*)d_ws;
    ushort_t* dbf  = (ushort_t*)(ws + 0);                    // 16,777,216
    ushort_t* sbf  = (ushort_t*)(ws + 16777216);             //  4,194,304
    ushort_t* W1bf = (ushort_t*)(ws + 20971520);             // 16,777,216
    ushort_t* W2bf = (ushort_t*)(ws + 37748736);             //  4,194,304
    ushort_t* Wb1T = (ushort_t*)(ws + 41943040);             // 67,108,864
    ushort_t* Wb2T = (ushort_t*)(ws + 109051904);            // 50,331,648
    ushort_t* xbf  = (ushort_t*)(ws + 171966464);            //  6,291,456
    float*    hpre = (float*)   (ws + 178257920);            // 33,554,432
    ushort_t* hbf  = (ushort_t*)(ws + 211812352);            // 16,777,216
    ushort_t* ybf  = (ushort_t*)(ws + 228589568);            // 50,331,648
    // xacc (B x 7168 f32 = 29,360,128 B) aliases hpre: xacc is fully consumed
    // by norm_silu_1024_k before stage 2 writes hpre.
    float*    xacc = hpre;

    // ---- prep: casts + transposes ----
    cast4_k<<<20480, 256, 0, stream>>>(deter, dbf, 2097152,
                                       stoch, sbf, 524288,
                                       W1, W1bf, 2097152,
                                       W2, W2bf);
    transpose_cast_k<<<dim3(32, 128, 8), dim3(8, 32), 0, stream>>>(Wb1, Wb1T, 4096, 1024);
    transpose_cast_k<<<dim3(96, 32, 8), dim3(8, 32), 0, stream>>>(Wb2, Wb2T, 1024, 3072);

    // ---- stage 1: three branches -> xacc planes (B,7168) f32, no atomics ----
    gemm_bt_k<0, false><<<dim3(16, 8, 4), 256, 0, stream>>>(
        dbf, nullptr, W1bf, xacc, nullptr, 8192, 8192, 7168, 2048, 0, 1024);
    gemm_bt_k<0, false><<<dim3(16, 8, 2), 256, 0, stream>>>(
        sbf, nullptr, W2bf, xacc + 4096, nullptr, 2048, 2048, 7168, 1024, 0, 1024);
    branch3_k<<<4096, 256, 0, stream>>>(action, W3, xacc);

    // ---- norm+silu with plane reduction -> xbf (B,3072) bf16 ----
    norm_silu_1024_k<<<dim3(1024, 3), 256, 0, stream>>>(xacc, b1, s1, b2, s2, b3, s3, xbf);

    // ---- stage 2: grouped GEMM Wb1 -> hpre (B,8192) f32 ----
    gemm_bt_k<1, false><<<dim3(16, 64, 1), 256, 0, stream>>>(
        xbf, dbf, Wb1T, hpre, nullptr, 0, 4096, 8192, 4096, 0, 0);

    // ---- norm+silu over 8192 -> hbf bf16 ----
    norm_silu_8192_k<<<1024, 256, 0, stream>>>(hpre, bb1, sb1, hbf);

    // ---- stage 3: grouped GEMM Wb2 -> ybf (B,24576) bf16 ----
    gemm_bt_k<2, true><<<dim3(16, 192, 1), 256, 0, stream>>>(
        hbf, nullptr, Wb2T, nullptr, ybf, 0, 1024, 24576, 1024, 0, 0);

    // ---- gates -> out (B,8192) f32 ----
    gates_k<<<8192, 256, 0, stream>>>(ybf, bb2, deter, out);
}

// Round 5
// 586.808 us; speedup vs baseline: 1.0638x; 1.0638x over previous
//
#include <hip/hip_runtime.h>
#include <stdint.h>

typedef unsigned short ushort_t;
typedef __attribute__((ext_vector_type(8))) short bf16x8;
typedef __attribute__((ext_vector_type(4))) float f32x4;

#define EPS 1e-6f

__device__ __forceinline__ float b2f(ushort_t u) {
    union { uint32_t i; float f; } v; v.i = ((uint32_t)u) << 16; return v.f;
}
__device__ __forceinline__ ushort_t f2b(float f) {
    union { float f; uint32_t i; } v; v.f = f;
    uint32_t x = v.i;
    uint32_t r = (x + 0x7fffu + ((x >> 16) & 1u)) >> 16;
    return (ushort_t)r;
}

__device__ __forceinline__ void async_copy16(const void* g, void* l) {
    __builtin_amdgcn_global_load_lds(
        (const __attribute__((address_space(1))) uint32_t*)(uintptr_t)g,
        (__attribute__((address_space(3))) uint32_t*)(uintptr_t)l,
        16, 0, 0);
}

// ---------------- fused f32 -> bf16 casts (4 tensors, one dispatch) ----------------
__global__ __launch_bounds__(256) void cast4_k(
    const float* __restrict__ s0, ushort_t* __restrict__ d0, int n0,
    const float* __restrict__ s1, ushort_t* __restrict__ d1, int n1,
    const float* __restrict__ s2, ushort_t* __restrict__ d2, int n2,
    const float* __restrict__ s3, ushort_t* __restrict__ d3) {
    int j = blockIdx.x * 256 + threadIdx.x;
    const float* s; ushort_t* d;
    if (j < n0) { s = s0; d = d0; }
    else if ((j -= n0) < n1) { s = s1; d = d1; }
    else if ((j -= n1) < n2) { s = s2; d = d2; }
    else { j -= n2; s = s3; d = d3; }
    float4 v = ((const float4*)s)[j];
    ushort4 o;
    o.x = f2b(v.x); o.y = f2b(v.y); o.z = f2b(v.z); o.w = f2b(v.w);
    ((ushort4*)d)[j] = o;
}

// ---- batched transpose + cast: src (batch,R,C) f32 -> dst (batch,C,R) bf16 ----
__global__ __launch_bounds__(256) void transpose_cast_k(const float* __restrict__ src,
                                                        ushort_t* __restrict__ dst,
                                                        int R, int C) {
    __shared__ float tile[32][33];
    int bat = blockIdx.z;
    int c0 = blockIdx.x * 32, r0 = blockIdx.y * 32;
    const float* s = src + (size_t)bat * R * C;
    ushort_t* d = dst + (size_t)bat * R * C;
    int tx = threadIdx.x, ty = threadIdx.y;   // blockDim (8,32)
    float4 v = *(const float4*)&s[(size_t)(r0 + ty) * C + c0 + tx * 4];
    tile[ty][tx * 4 + 0] = v.x;
    tile[ty][tx * 4 + 1] = v.y;
    tile[ty][tx * 4 + 2] = v.z;
    tile[ty][tx * 4 + 3] = v.w;
    __syncthreads();
    ushort4 o;
    o.x = f2b(tile[tx * 4 + 0][ty]);
    o.y = f2b(tile[tx * 4 + 1][ty]);
    o.z = f2b(tile[tx * 4 + 2][ty]);
    o.w = f2b(tile[tx * 4 + 3][ty]);
    *(ushort4*)&d[(size_t)(c0 + ty) * R + r0 + tx * 4] = o;
}

// ---------------- MFMA GEMM: C[m,n] = sum_k A[m,k] * B[n,k], bf16 in, f32 acc --------
// v5: generic tile (BM x BN, BK=64), WNW n-waves x 2 m-waves, THREADS = WNW*128.
//     cfg128 <128,128,2>: 256 thr, 64 KB LDS, 2 blk/CU  (= proven v3b geometry)
//     cfg256 <256,256,4>: 512 thr, 128 KB LDS, 1 blk/CU (2x FLOP per staged byte —
//     staging-BW model from R4 post-mortem predicts ~55% MfmaUtil)
//     Sync structure identical to v3b (passed twice): double-buffered, counted
//     vmcnt(8), raw s_barrier pair + sched_barrier(0) pins, 8-slot XOR swizzle
//     (pre-swizzled global source + swizzled ds_read), XCD-aware remap,
//     plane-split output via czoff.
// MODE 0: A = Aa (M x lda)
// MODE 1: A(m,k) = k<3072 ? x[m,3072]+k : dbf[m,8192] + g*1024 + (k-3072), g = n0/1024
// MODE 2: A(m,k) = hbf[m,8192] + g*1024 + k, g = n0/3072
template <int MODE, bool OUT_BF16, int BM, int BN, int WNW>
__global__ __launch_bounds__(WNW * 128, 2) void gemm_bt_k(
    const ushort_t* __restrict__ Aa, const ushort_t* __restrict__ Ab,
    const ushort_t* __restrict__ Bw,
    float* __restrict__ Cf, ushort_t* __restrict__ Cb,
    int lda, int ldb, int ldc, int Ksl, int k0base, int czoff) {
    constexpr int THREADS = WNW * 128;
    constexpr int MR = (BM / 2) / 16;        // m-frags per wave
    constexpr int NR = (BN / WNW) / 16;      // n-frags per wave (=4)
    constexpr int SR = THREADS >> 3;         // staging rows per pass (32 or 64)
    __shared__ __align__(16) ushort_t As[2][BM * 64];
    __shared__ __align__(16) ushort_t Bs[2][BN * 64];
    const int tid = threadIdx.x;

    // XCD-aware remap: nxy % 8 == 0 in all launches; bijective.
    const int gx = gridDim.x;
    const int nxy = gx * gridDim.y;
    const int flat = blockIdx.x + blockIdx.y * gx;
    const int cpx = nxy >> 3;
    const int L = (flat & 7) * cpx + (flat >> 3);
    const int bm = L % gx, bn = L / gx;
    const int bz = blockIdx.z;
    const int k0 = k0base + bz * Ksl;
    const int m0 = bm * BM, n0 = bn * BN;
    const int cz = bz * czoff;                  // plane-split column shift
    const int lane = tid & 63, w = tid >> 6;
    const int wm = (w & 1) * (BM / 2);
    const int wn = (w >> 1) * (BN / WNW);

    f32x4 acc[MR][NR];
#pragma unroll
    for (int i = 0; i < MR; i++)
#pragma unroll
        for (int j = 0; j < NR; j++) acc[i][j] = (f32x4){0.f, 0.f, 0.f, 0.f};

    auto a_ptr = [&](int m, int kk) -> const ushort_t* {
        if (MODE == 0) {
            return Aa + (size_t)m * lda + kk;
        } else if (MODE == 1) {
            if (kk < 3072) return Aa + (size_t)m * 3072 + kk;
            int g = n0 >> 10;
            return Ab + (size_t)m * 8192 + g * 1024 + (kk - 3072);
        } else {
            int g = n0 / 3072;
            return Aa + (size_t)m * 8192 + g * 1024 + kk;
        }
    };

    // Staging geometry: thread -> (row = tid>>3, slot = tid&7).
    // LDS dest linear in tid (global_load_lds requirement); the 8-slot XOR
    // swizzle is applied on the GLOBAL source k-chunk (both-sides involution).
    const int srow = tid >> 3;
    const int sslot = tid & 7;
    const int gco = (sslot ^ (srow & 7)) << 3;   // swizzled global k-chunk (elems)
    const int lco = sslot << 3;                  // linear LDS chunk (elems)

    auto stage = [&](int buf, int kk) {          // 8 global_load_lds per thread
#pragma unroll
        for (int p = 0; p < BM / SR; ++p) {
            int r = p * SR + srow;               // SR % 8 == 0 -> r&7 == srow&7
            async_copy16(a_ptr(m0 + r, kk + gco), &As[buf][r * 64 + lco]);
        }
#pragma unroll
        for (int p = 0; p < BN / SR; ++p) {
            int r = p * SR + srow;
            async_copy16(Bw + (size_t)(n0 + r) * ldb + kk + gco, &Bs[buf][r * 64 + lco]);
        }
    };

    const int nt = Ksl >> 6;                     // 64-wide K tiles
    stage(0, k0);
    __builtin_amdgcn_sched_barrier(0);           // pin prologue stage above loop

    const int qc = lane >> 4;                    // k-chunk within 32 (0..3)
    const int rl = lane & 15;
    int cur = 0;

    for (int t = 0; t < nt; ++t) {
        if (t + 1 < nt) {
            stage(cur ^ 1, k0 + ((t + 1) << 6)); // issue next tile (8 loads)
            asm volatile("s_waitcnt vmcnt(8)" ::: "memory");  // wait tile t only
        } else {
            asm volatile("s_waitcnt vmcnt(0)" ::: "memory");
        }
        __builtin_amdgcn_s_barrier();            // publish tile t to all waves
        __builtin_amdgcn_sched_barrier(0);

#pragma unroll
        for (int h = 0; h < 2; ++h) {            // two K=32 halves of the tile
            bf16x8 af[MR], bfr[NR];
#pragma unroll
            for (int i = 0; i < MR; i++) {
                int ra = wm + i * 16 + rl;
                int slot = ((h << 2) + qc) ^ (ra & 7);
                af[i] = *(const bf16x8*)&As[cur][ra * 64 + (slot << 3)];
            }
#pragma unroll
            for (int j = 0; j < NR; j++) {
                int rb = wn + j * 16 + rl;
                int slot = ((h << 2) + qc) ^ (rb & 7);
                bfr[j] = *(const bf16x8*)&Bs[cur][rb * 64 + (slot << 3)];
            }
#pragma unroll
            for (int i = 0; i < MR; i++)
#pragma unroll
                for (int j = 0; j < NR; j++)
                    acc[i][j] = __builtin_amdgcn_mfma_f32_16x16x32_bf16(af[i], bfr[j], acc[i][j], 0, 0, 0);
        }

        if (t + 1 < nt) {
            __builtin_amdgcn_sched_barrier(0);   // keep all tile-t reads above
            __builtin_amdgcn_s_barrier();        // reads done before overwrite
            __builtin_amdgcn_sched_barrier(0);   // keep next stage below
            cur ^= 1;
        }
    }

    const int cr = (lane >> 4) * 4, cc = lane & 15;
#pragma unroll
    for (int i = 0; i < MR; i++) {
#pragma unroll
        for (int j = 0; j < NR; j++) {
#pragma unroll
            for (int r = 0; r < 4; r++) {
                int row = m0 + wm + i * 16 + cr + r;
                int col = n0 + cz + wn + j * 16 + cc;
                float v = acc[i][j][r];
                if (OUT_BF16) {
                    Cb[(size_t)row * ldc + col] = f2b(v);
                } else {
                    Cf[(size_t)row * ldc + col] = v;
                }
            }
        }
    }
}

// ---------------- branch 3 (K=2): xacc[:, 6144:7168] = a_norm @ W3.T ----------------
__global__ __launch_bounds__(256) void branch3_k(const float* __restrict__ act,
                                                 const float* __restrict__ W3,
                                                 float* __restrict__ xacc) {
    int idx = blockIdx.x * 256 + threadIdx.x;   // over B*1024
    int b = idx >> 10, h = idx & 1023;
    float a0 = act[b * 2 + 0], a1 = act[b * 2 + 1];
    a0 = a0 / fmaxf(1.f, fabsf(a0));
    a1 = a1 / fmaxf(1.f, fabsf(a1));
    float v = a0 * W3[h * 2 + 0] + a1 * W3[h * 2 + 1];
    xacc[(size_t)b * 7168 + 6144 + h] = v;
}

// ------- RMSNorm(1024)+SiLU per (b, chunk) with plane reduction, out bf16 -------
// xacc row layout (7168 f32): [c0: 4 planes x1024][c1: 2 planes x1024][c2: 1x1024]
__global__ __launch_bounds__(256) void norm_silu_1024_k(
    const float* __restrict__ xacc,
    const float* __restrict__ b1, const float* __restrict__ s1,
    const float* __restrict__ b2, const float* __restrict__ s2,
    const float* __restrict__ b3, const float* __restrict__ s3,
    ushort_t* __restrict__ xbf) {
    int b = blockIdx.x, c = blockIdx.y, tid = threadIdx.x;
    const float* bias = (c == 0) ? b1 : (c == 1) ? b2 : b3;
    const float* scl  = (c == 0) ? s1 : (c == 1) ? s2 : s3;
    const float* row = xacc + (size_t)b * 7168 + ((c == 0) ? 0 : (c == 1) ? 4096 : 6144);
    const int np = (c == 0) ? 4 : (c == 1) ? 2 : 1;
    float4 v = ((const float4*)row)[tid];
#pragma unroll 4
    for (int p = 1; p < np; ++p) {
        float4 t = ((const float4*)(row + p * 1024))[tid];
        v.x += t.x; v.y += t.y; v.z += t.z; v.w += t.w;
    }
    float4 bb = ((const float4*)bias)[tid];
    v.x += bb.x; v.y += bb.y; v.z += bb.z; v.w += bb.w;
    float ss = v.x * v.x + v.y * v.y + v.z * v.z + v.w * v.w;
#pragma unroll
    for (int off = 32; off > 0; off >>= 1) ss += __shfl_down(ss, off, 64);
    __shared__ float wsum[4];
    int lane = tid & 63, wid = tid >> 6;
    if (lane == 0) wsum[wid] = ss;
    __syncthreads();
    float tot = wsum[0] + wsum[1] + wsum[2] + wsum[3];
    float rms = rsqrtf(tot * (1.0f / 1024.0f) + EPS);
    float4 sc = ((const float4*)scl)[tid];
    float o0 = v.x * rms * sc.x; o0 = o0 / (1.f + __expf(-o0));
    float o1 = v.y * rms * sc.y; o1 = o1 / (1.f + __expf(-o1));
    float o2 = v.z * rms * sc.z; o2 = o2 / (1.f + __expf(-o2));
    float o3 = v.w * rms * sc.w; o3 = o3 / (1.f + __expf(-o3));
    ushort4 o; o.x = f2b(o0); o.y = f2b(o1); o.z = f2b(o2); o.w = f2b(o3);
    ((ushort4*)(xbf + (size_t)b * 3072 + c * 1024))[tid] = o;
}

// ------- RMSNorm(8192)+SiLU per row with 2-plane reduction, out bf16 -------
// hpre2 row layout (16384 f32): [plane0: 8192][plane1: 8192]
__global__ __launch_bounds__(256) void norm_silu_8192_k(const float* __restrict__ hpre,
                                                        const float* __restrict__ bb1,
                                                        const float* __restrict__ sb1,
                                                        ushort_t* __restrict__ hbf) {
    int b = blockIdx.x, tid = threadIdx.x;
    const float4* src = (const float4*)(hpre + (size_t)b * 16384);
    float4 v[8];
    float ss = 0.f;
#pragma unroll
    for (int k = 0; k < 8; k++) {
        float4 t = src[tid + k * 256];
        float4 u = src[tid + k * 256 + 2048];      // plane 1
        t.x += u.x; t.y += u.y; t.z += u.z; t.w += u.w;
        float4 bv = ((const float4*)bb1)[tid + k * 256];
        t.x += bv.x; t.y += bv.y; t.z += bv.z; t.w += bv.w;
        v[k] = t;
        ss += t.x * t.x + t.y * t.y + t.z * t.z + t.w * t.w;
    }
#pragma unroll
    for (int off = 32; off > 0; off >>= 1) ss += __shfl_down(ss, off, 64);
    __shared__ float wsum[4];
    int lane = tid & 63, wid = tid >> 6;
    if (lane == 0) wsum[wid] = ss;
    __syncthreads();
    float tot = wsum[0] + wsum[1] + wsum[2] + wsum[3];
    float rms = rsqrtf(tot * (1.0f / 8192.0f) + EPS);
    ushort_t* dst = hbf + (size_t)b * 8192;
#pragma unroll
    for (int k = 0; k < 8; k++) {
        float4 sv = ((const float4*)sb1)[tid + k * 256];
        float o0 = v[k].x * rms * sv.x; o0 = o0 / (1.f + __expf(-o0));
        float o1 = v[k].y * rms * sv.y; o1 = o1 / (1.f + __expf(-o1));
        float o2 = v[k].z * rms * sv.z; o2 = o2 / (1.f + __expf(-o2));
        float o3 = v[k].w * rms * sv.w; o3 = o3 / (1.f + __expf(-o3));
        ushort4 o; o.x = f2b(o0); o.y = f2b(o1); o.z = f2b(o2); o.w = f2b(o3);
        ((ushort4*)dst)[tid + k * 256] = o;
    }
}

// ---------------- gate combine ----------------
__global__ __launch_bounds__(256) void gates_k(const ushort_t* __restrict__ y,
                                               const float* __restrict__ bb2,
                                               const float* __restrict__ deter,
                                               float* __restrict__ out) {
    int idx = blockIdx.x * 256 + threadIdx.x;    // over B*8192/4
    int f = idx * 4;
    int b = f >> 13, d = f & 8191;
    int g = d >> 10, j = d & 1023;
    size_t ybase = (size_t)b * 24576 + g * 3072 + j;
    ushort4 rv = *(const ushort4*)(y + ybase);
    ushort4 cv = *(const ushort4*)(y + ybase + 1024);
    ushort4 uv = *(const ushort4*)(y + ybase + 2048);
    float4 bbr = *(const float4*)(bb2 + g * 3072 + j);
    float4 bbc = *(const float4*)(bb2 + g * 3072 + 1024 + j);
    float4 bbu = *(const float4*)(bb2 + g * 3072 + 2048 + j);
    float4 dv = *(const float4*)(deter + f);
    float rr[4] = {b2f(rv.x) + bbr.x, b2f(rv.y) + bbr.y, b2f(rv.z) + bbr.z, b2f(rv.w) + bbr.w};
    float cc[4] = {b2f(cv.x) + bbc.x, b2f(cv.y) + bbc.y, b2f(cv.z) + bbc.z, b2f(cv.w) + bbc.w};
    float uu[4] = {b2f(uv.x) + bbu.x, b2f(uv.y) + bbu.y, b2f(uv.z) + bbu.z, b2f(uv.w) + bbu.w};
    float dd[4] = {dv.x, dv.y, dv.z, dv.w};
    float oo[4];
#pragma unroll
    for (int t = 0; t < 4; t++) {
        float reset = 1.f / (1.f + __expf(-rr[t]));
        float cand = tanhf(reset * cc[t]);
        float upd = 1.f / (1.f + __expf(-(uu[t] - 1.f)));
        oo[t] = upd * cand + (1.f - upd) * dd[t];
    }
    float4 o; o.x = oo[0]; o.y = oo[1]; o.z = oo[2]; o.w = oo[3];
    *(float4*)(out + f) = o;
}

extern "C" void kernel_launch(void* const* d_in, const int* in_sizes, int n_in,
                              void* d_out, int out_size, void* d_ws, size_t ws_size,
                              hipStream_t stream) {
    const float* deter = (const float*)d_in[0];
    const float* stoch = (const float*)d_in[1];
    const float* action = (const float*)d_in[2];
    const float* W1 = (const float*)d_in[3];
    const float* b1 = (const float*)d_in[4];
    const float* s1 = (const float*)d_in[5];
    const float* W2 = (const float*)d_in[6];
    const float* b2 = (const float*)d_in[7];
    const float* s2 = (const float*)d_in[8];
    const float* W3 = (const float*)d_in[9];
    const float* b3 = (const float*)d_in[10];
    const float* s3 = (const float*)d_in[11];
    const float* Wb1 = (const float*)d_in[12];
    const float* bb1 = (const float*)d_in[13];
    const float* sb1 = (const float*)d_in[14];
    const float* Wb2 = (const float*)d_in[15];
    const float* bb2 = (const float*)d_in[16];
    float* out = (float*)d_out;

    char* ws = (char*)d_ws;
    ushort_t* dbf   = (ushort_t*)(ws + 0);                   // 16,777,216
    ushort_t* sbf   = (ushort_t*)(ws + 16777216);            //  4,194,304
    ushort_t* W1bf  = (ushort_t*)(ws + 20971520);            // 16,777,216
    ushort_t* W2bf  = (ushort_t*)(ws + 37748736);            //  4,194,304
    ushort_t* Wb1T  = (ushort_t*)(ws + 41943040);            // 67,108,864
    ushort_t* Wb2T  = (ushort_t*)(ws + 109051904);           // 50,331,648
    ushort_t* xbf   = (ushort_t*)(ws + 159383552);           //  6,291,456
    float*    hpre2 = (float*)   (ws + 165675008);           // 67,108,864 (B x 16384)
    ushort_t* hbf   = (ushort_t*)(ws + 232783872);           // 16,777,216 -> ends 249,561,088
    // Sequential aliases of the hpre2 region (each fully consumed before the
    // next producer writes):
    //   xacc (B x 7168 f32 = 29,360,128)  -- consumed by norm_silu_1024_k
    //   ybf  (B x 24576 bf16 = 50,331,648) -- written by stage 3 after
    //        norm_silu_8192_k has consumed hpre2
    float*    xacc = hpre2;
    ushort_t* ybf  = (ushort_t*)hpre2;

    // ---- prep: casts + transposes ----
    cast4_k<<<20480, 256, 0, stream>>>(deter, dbf, 2097152,
                                       stoch, sbf, 524288,
                                       W1, W1bf, 2097152,
                                       W2, W2bf);
    transpose_cast_k<<<dim3(32, 128, 8), dim3(8, 32), 0, stream>>>(Wb1, Wb1T, 4096, 1024);
    transpose_cast_k<<<dim3(96, 32, 8), dim3(8, 32), 0, stream>>>(Wb2, Wb2T, 1024, 3072);

    // ---- stage 1: three branches -> xacc planes (B,7168) f32, cfg128 ----
    gemm_bt_k<0, false, 128, 128, 2><<<dim3(8, 8, 4), 256, 0, stream>>>(
        dbf, nullptr, W1bf, xacc, nullptr, 8192, 8192, 7168, 2048, 0, 1024);
    gemm_bt_k<0, false, 128, 128, 2><<<dim3(8, 8, 2), 256, 0, stream>>>(
        sbf, nullptr, W2bf, xacc + 4096, nullptr, 2048, 2048, 7168, 1024, 0, 1024);
    branch3_k<<<4096, 256, 0, stream>>>(action, W3, xacc);

    // ---- norm+silu with plane reduction -> xbf (B,3072) bf16 ----
    norm_silu_1024_k<<<dim3(1024, 3), 256, 0, stream>>>(xacc, b1, s1, b2, s2, b3, s3, xbf);

    // ---- stage 2: grouped GEMM Wb1 -> hpre2 (B,2,8192) f32, cfg256, z-split K ----
    gemm_bt_k<1, false, 256, 256, 4><<<dim3(4, 32, 2), 512, 0, stream>>>(
        xbf, dbf, Wb1T, hpre2, nullptr, 0, 4096, 16384, 2048, 0, 8192);

    // ---- norm+silu over 8192 (2-plane sum) -> hbf bf16 ----
    norm_silu_8192_k<<<1024, 256, 0, stream>>>(hpre2, bb1, sb1, hbf);

    // ---- stage 3: grouped GEMM Wb2 -> ybf (B,24576) bf16, cfg256 ----
    gemm_bt_k<2, true, 256, 256, 4><<<dim3(4, 96, 1), 512, 0, stream>>>(
        hbf, nullptr, Wb2T, nullptr, ybf, 0, 1024, 24576, 1024, 0, 0);

    // ---- gates -> out (B,8192) f32 ----
    gates_k<<<8192, 256, 0, stream>>>(ybf, bb2, deter, out);
}